// Round 15
// baseline (127.083 us; speedup 1.0000x reference)
//
#include <hip/hip_runtime.h>
#include <hip/hip_bf16.h>
#include <math.h>

#define SEQ 4096
#define HD  64
#define NBATCH 4

#define EM1   1.71828182845904523536f
#define INVD5 (1.0f/(4096.f + 5.f*EM1))
#define INVD4 (1.0f/(4096.f + 4.f*EM1))
#define INVD3 (1.0f/(4096.f + 3.f*EM1))

typedef __attribute__((ext_vector_type(8))) short short8;
typedef __attribute__((ext_vector_type(4))) float f32x4;

__device__ __forceinline__ f32x4 mfma16(short8 a, short8 b, f32x4 c) {
    return __builtin_amdgcn_mfma_f32_16x16x32_bf16(a, b, c, 0, 0, 0);
}

__device__ __forceinline__ short bfs(float x) {
    __hip_bfloat16 h = __float2bfloat16(x);
    return *(short*)&h;
}

__device__ __forceinline__ short8 pack8(float4 a, float4 b) {
    short8 r;
    r[0] = bfs(a.x); r[1] = bfs(a.y); r[2] = bfs(a.z); r[3] = bfs(a.w);
    r[4] = bfs(b.x); r[5] = bfs(b.y); r[6] = bfs(b.z); r[7] = bfs(b.w);
    return r;
}

__device__ __forceinline__ float b2f(__hip_bfloat16 h) { return __bfloat162float(h); }
__device__ __forceinline__ float sb2f(short s) {
    return __uint_as_float(((unsigned)(unsigned short)s) << 16);
}

// ---------------------------------------------------------------------------
// Kernel 0: prepack W to bf16 (Wq scaled by exact 0.125) + zero done-counters.
// ---------------------------------------------------------------------------
__global__ __launch_bounds__(256) void wpack_kernel(
    const float* __restrict__ Wq, const float* __restrict__ Wk,
    const float* __restrict__ Wv, __hip_bfloat16* __restrict__ Wb,
    int* __restrict__ Mcount)
{
    const int blk = blockIdx.x, tid = threadIdx.x;
    if (blk == 0 && tid < NBATCH) Mcount[tid] = 0;
    const float* W = (blk == 0) ? Wq : (blk == 1) ? Wk : Wv;
    const float s = (blk == 0) ? 0.125f : 1.f;
    const float* src = W + tid * 16;
    float4 a0 = *(const float4*)(src);
    float4 a1 = *(const float4*)(src + 4);
    float4 a2 = *(const float4*)(src + 8);
    float4 a3 = *(const float4*)(src + 12);
    a0.x*=s; a0.y*=s; a0.z*=s; a0.w*=s;
    a1.x*=s; a1.y*=s; a1.z*=s; a1.w*=s;
    a2.x*=s; a2.y*=s; a2.z*=s; a2.w*=s;
    a3.x*=s; a3.y*=s; a3.z*=s; a3.w*=s;
    __hip_bfloat16* dst = Wb + blk * 4096 + tid * 16;
    *(short8*)(dst)     = pack8(a0, a1);
    *(short8*)(dst + 8) = pack8(a2, a3);
}

// ---------------------------------------------------------------------------
// Kernel 1: fused projection + M-chunk GEMM + (last block per batch) final
// reduction.  512 blocks x 256 thr.  Wave (rg,cg): rows rg*16, cols cg*32.
// Tail: device-fence + atomic done-counter; the 128th block of each batch
// reduces Mpart -> MTm and computes mktot/ktot/VDs/Vtot (rocPRIM pattern).
// ---------------------------------------------------------------------------
__global__ __launch_bounds__(256) void projm_kernel(
    const float* __restrict__ feat, const __hip_bfloat16* __restrict__ Wb,
    const float* __restrict__ bq, const float* __restrict__ bk,
    const float* __restrict__ bv,
    __hip_bfloat16* __restrict__ qsb, float* __restrict__ kpart,
    float* __restrict__ vpart, __hip_bfloat16* __restrict__ Mpart,
    float* __restrict__ kedge, int* __restrict__ Mcount,
    __hip_bfloat16* __restrict__ MTm, float* __restrict__ mktotF,
    float* __restrict__ ktotF, float* __restrict__ VDs,
    float* __restrict__ VtotF)
{
    __shared__ __hip_bfloat16 kT[64 * 40];    // [h][t-local 0..31]
    __shared__ __hip_bfloat16 vT[64 * 40];    // [h][idx 0..35] = t0-2 .. t0+33
    __shared__ __hip_bfloat16 lvt[64 * 40];   // locv5^T [h][t-local 0..31]
    __shared__ float kred[4][32];
    __shared__ float vred[4][32];
    __shared__ __hip_bfloat16 stage[4][16][64];   // reducer MTm staging
    __shared__ float redk[4][64];
    __shared__ float redv2[4][64];
    __shared__ int amLast;

    const int tid  = threadIdx.x;
    const int wave = tid >> 6, lane = tid & 63;
    const int rg = wave >> 1, cg = wave & 1;
    const int quad = lane >> 4, ln = lane & 15;
    const int R0 = blockIdx.x * 32;            // [0, B*S)
    const int b  = R0 >> 12;
    const int t0 = R0 & (SEQ - 1);
    const int chunk = blockIdx.x & 127;

    // A-fragments for this wave's 16 rows
    short8 af0, af1;
    {
        const float* fp = feat + (size_t)(R0 + rg * 16 + ln) * HD + quad * 8;
        af0 = pack8(*(const float4*)(fp),      *(const float4*)(fp + 4));
        af1 = pack8(*(const float4*)(fp + 32), *(const float4*)(fp + 36));
    }

    // halo A-fragments: rg=0 -> rows t0-2,t0-1 (lanes 0,1); rg=1 -> t0+32,+33
    short8 hf0, hf1;
    const bool hflag = (rg == 0) ? (t0 > 0) : (t0 < SEQ - 32);
    {
        const int hrow = (rg == 0) ? (t0 - 2 + ln) : (t0 + 32 + ln);
        if (ln < 2 && hflag) {
            const float* fp = feat + ((size_t)(b << 12) + hrow) * HD + quad * 8;
            hf0 = pack8(*(const float4*)(fp),      *(const float4*)(fp + 4));
            hf1 = pack8(*(const float4*)(fp + 32), *(const float4*)(fp + 36));
        } else {
            #pragma unroll
            for (int j = 0; j < 8; ++j) { hf0[j] = 0; hf1[j] = 0; }
        }
    }

    const float* Bs[3] = {bq, bk, bv};

    #pragma unroll
    for (int m = 0; m < 3; ++m) {
        const __hip_bfloat16* W = Wb + m * 4096;
        const float* bias = Bs[m];
        #pragma unroll
        for (int ctp = 0; ctp < 2; ++ctp) {
            const int col = cg * 32 + ctp * 16 + ln;
            const __hip_bfloat16* wp = W + col * 64 + quad * 8;
            short8 b0 = *(const short8*)(wp);
            short8 b1 = *(const short8*)(wp + 32);
            f32x4 c = {};
            c = mfma16(af0, b0, c);
            c = mfma16(af1, b1, c);

            if (m == 0) {
                const float bl = bias[col] * 0.125f;
                #pragma unroll
                for (int r = 0; r < 4; ++r)
                    qsb[(size_t)(R0 + rg * 16 + quad * 4 + r) * HD + col] =
                        __float2bfloat16(c[r] + bl);
            } else if (m == 1) {
                const float bl = bias[col];
                float tot = c[0] + c[1] + c[2] + c[3];
                tot += __shfl_xor(tot, 16);
                tot += __shfl_xor(tot, 32);
                if (quad == 0) kred[wave][ctp * 16 + ln] = tot;
                #pragma unroll
                for (int r = 0; r < 4; ++r)
                    kT[col * 40 + rg * 16 + quad * 4 + r] =
                        __float2bfloat16(c[r] + bl);
            } else {
                const float bl = bias[col];
                float tot = c[0] + c[1] + c[2] + c[3];
                tot += __shfl_xor(tot, 16);
                tot += __shfl_xor(tot, 32);
                if (quad == 0) vred[wave][ctp * 16 + ln] = tot;
                #pragma unroll
                for (int r = 0; r < 4; ++r)
                    vT[col * 40 + 2 + rg * 16 + quad * 4 + r] =
                        __float2bfloat16(c[r] + bl);
                f32x4 hc = {};
                hc = mfma16(hf0, b0, hc);
                hc = mfma16(hf1, b1, hc);
                if (quad == 0) {
                    const int base = (rg == 0) ? 0 : 34;
                    vT[col * 40 + base]     = __float2bfloat16(hflag ? hc[0] + bl : 0.f);
                    vT[col * 40 + base + 1] = __float2bfloat16(hflag ? hc[1] + bl : 0.f);
                }
            }
        }
    }
    __syncthreads();

    if (tid < 64) {
        const int col = tid, cg2 = col >> 5, cl = col & 31;
        kpart[(size_t)blockIdx.x * 64 + col] =
            kred[cg2][cl] + kred[2 + cg2][cl] + 32.f * bk[col];
        vpart[(size_t)blockIdx.x * 64 + col] =
            vred[cg2][cl] + vred[2 + cg2][cl] + 32.f * bv[col];
    }

    // locv5^T: thread (h = tid&63, tb = wave*8) -> 8 t's; vector LDS ops
    {
        const int h = tid & 63;
        const int tb = wave * 8;
        short8 v0 = *(const short8*)&vT[h * 40 + tb];
        short8 v1 = *(const short8*)&vT[h * 40 + tb + 8];
        float w[12];
        #pragma unroll
        for (int j = 0; j < 8; ++j) w[j] = sb2f(v0[j]);
        #pragma unroll
        for (int j = 0; j < 4; ++j) w[8 + j] = sb2f(v1[j]);
        short8 o;
        #pragma unroll
        for (int i = 0; i < 8; ++i)
            o[i] = bfs(w[i] + w[i+1] + w[i+2] + w[i+3] + w[i+4]);
        *(short8*)&lvt[h * 40 + tb] = o;
    }

    // export edge k rows for mktot closed form
    if (chunk == 0) {
        const int t = tid >> 6, h = tid & 63;
        kedge[b * 512 + t * 64 + h] = b2f(kT[h * 40 + t]);
    } else if (chunk == 127) {
        const int t = tid >> 6, h = tid & 63;
        kedge[b * 512 + (4 + t) * 64 + h] = b2f(kT[h * 40 + 28 + t]);
    }
    __syncthreads();

    // M-GEMM: wave owns h1-strip = wave*16, K=32, 4 MFMAs/wave
    __hip_bfloat16* mp = Mpart + (size_t)(b * 128 + chunk) * 4096;
    {
        const int strip = wave;
        short8 a = *(const short8*)&kT[(strip * 16 + ln) * 40 + quad * 8];
        #pragma unroll
        for (int ct = 0; ct < 4; ++ct) {
            short8 bb = *(const short8*)&lvt[(ct * 16 + ln) * 40 + quad * 8];
            f32x4 acc = {};
            acc = mfma16(a, bb, acc);
            #pragma unroll
            for (int r = 0; r < 4; ++r)
                mp[(strip * 16 + quad * 4 + r) * 64 + ct * 16 + ln] =
                    __float2bfloat16(acc[r]);
        }
    }

    // ---------------- last-block-per-batch reduction tail ----------------
    __syncthreads();
    if (tid == 0) {
        __threadfence();                              // release our stores
        amLast = (atomicAdd(&Mcount[b], 1) == 127);
    }
    __syncthreads();
    if (!amLast) return;
    __threadfence();                                  // acquire peers' stores

    // MTm: wave w reduces h1-strip [w*16, +16); shuffle-tree over chunks
    {
        const int ln8 = lane >> 3, vp = lane & 7;
        for (int r = 0; r < 16; ++r) {
            const int h1 = wave * 16 + r;
            float a[8] = {};
            for (int it = 0; it < 16; ++it) {
                const int c = it * 8 + ln8;
                short8 v = *(const short8*)&Mpart[(size_t)(b * 128 + c) * 4096
                                                  + h1 * 64 + vp * 8];
                #pragma unroll
                for (int e = 0; e < 8; ++e) a[e] += sb2f(v[e]);
            }
            #pragma unroll
            for (int e = 0; e < 8; ++e) {
                a[e] += __shfl_xor(a[e], 8);
                a[e] += __shfl_xor(a[e], 16);
                a[e] += __shfl_xor(a[e], 32);
            }
            if (ln8 == 0) {
                #pragma unroll
                for (int e = 0; e < 8; ++e)
                    stage[wave][r][vp * 8 + e] =
                        __float2bfloat16((EM1 * INVD5) * a[e]);
            }
        }
    }
    // prep partial sums in parallel with staging completion
    {
        const int g = tid >> 6, hh = tid & 63;
        float kp = 0.f, vp2 = 0.f;
        for (int j = 0; j < 32; ++j) {
            kp  += kpart[(size_t)(b * 128 + g * 32 + j) * 64 + hh];
            vp2 += vpart[(size_t)(b * 128 + g * 32 + j) * 64 + hh];
        }
        redk[g][hh] = kp;
        redv2[g][hh] = vp2;
    }
    __syncthreads();

    // transposed MTm store: 512 tasks = 64 h2 x 8 h1-octets
    #pragma unroll
    for (int i = 0; i < 2; ++i) {
        const int tsk = i * 256 + tid;
        const int h2 = tsk & 63, oct = tsk >> 6;
        const int w2 = oct >> 1, rb = (oct & 1) * 8;
        short8 o;
        #pragma unroll
        for (int j = 0; j < 8; ++j)
            o[j] = *(short*)&stage[w2][rb + j][h2];
        *(short8*)&MTm[(size_t)b * 4096 + h2 * 64 + oct * 8] = o;
    }

    if (tid < 64) {
        const int hh = tid;
        const float kt = redk[0][hh] + redk[1][hh] + redk[2][hh] + redk[3][hh];
        const float vt = redv2[0][hh] + redv2[1][hh] + redv2[2][hh] + redv2[3][hh];
        const float e0 = kedge[b * 512 + 0 * 64 + hh];
        const float e1 = kedge[b * 512 + 1 * 64 + hh];
        const float e2 = kedge[b * 512 + 2 * 64 + hh];
        const float e3 = kedge[b * 512 + 3 * 64 + hh];
        const float f0 = kedge[b * 512 + 4 * 64 + hh];
        const float f1 = kedge[b * 512 + 5 * 64 + hh];
        const float f2 = kedge[b * 512 + 6 * 64 + hh];
        const float f3 = kedge[b * 512 + 7 * 64 + hh];
        const float Sint = 5.f*kt - 4.f*e0 - 3.f*e1 - 2.f*e2 - e3
                         - f0 - 2.f*f1 - 3.f*f2 - 4.f*f3;
        const float SlocD = Sint * INVD5
                          + (e0+e1+e2 + f1+f2+f3) * INVD3
                          + (e0+e1+e2+e3 + f0+f1+f2+f3) * INVD4;
        mktotF[b * 64 + hh] = kt * (4092.f*INVD5 + 2.f*INVD4 + 2.f*INVD3) + EM1 * SlocD;
        ktotF[b * 64 + hh]  = kt;
        VDs[b * 64 + hh]    = INVD5 * vt;
        VtotF[b * 64 + hh]  = vt;
    }
}

// ---------------------------------------------------------------------------
// Kernel 2: out = (Vtot + qs·Mmain + (qs·ktot)·VDs) / (4096 + qs·mktot).
// grid 1024 x 64.  12 MFMAs; denominators & ktot-dot via uniform-B trick.
// ---------------------------------------------------------------------------
__global__ __launch_bounds__(64) void out_kernel(
    const __hip_bfloat16* __restrict__ qsb, const __hip_bfloat16* __restrict__ MTm,
    const float* __restrict__ mktotF, const float* __restrict__ ktotF,
    const float* __restrict__ VDs, const float* __restrict__ VtotF,
    float* __restrict__ out)
{
    const int tid = threadIdx.x;
    const int quad = tid >> 4, ln = tid & 15;
    const int R0 = blockIdx.x * 16;
    const int b = R0 >> 12;

    short8 qa0, qa1;
    {
        const __hip_bfloat16* qp = qsb + (size_t)(R0 + ln) * HD + quad * 8;
        qa0 = *(const short8*)qp;
        qa1 = *(const short8*)(qp + 32);
    }

    const __hip_bfloat16* mtb = MTm + (size_t)b * 4096;
    f32x4 acc[4];
    #pragma unroll
    for (int ct = 0; ct < 4; ++ct) {
        short8 b0 = *(const short8*)(mtb + (ct * 16 + ln) * 64 + quad * 8);
        short8 b1 = *(const short8*)(mtb + (ct * 16 + ln) * 64 + 32 + quad * 8);
        f32x4 c = {};
        c = mfma16(qa0, b0, c);
        c = mfma16(qa1, b1, c);
        acc[ct] = c;
    }

    short8 mk0, mk1, kt0, kt1;
    #pragma unroll
    for (int j = 0; j < 8; ++j) {
        mk0[j] = bfs(mktotF[b * 64 + quad * 8 + j]);
        mk1[j] = bfs(mktotF[b * 64 + 32 + quad * 8 + j]);
        kt0[j] = bfs(ktotF[b * 64 + quad * 8 + j]);
        kt1[j] = bfs(ktotF[b * 64 + 32 + quad * 8 + j]);
    }
    f32x4 accd = {}, acck = {};
    accd = mfma16(qa0, mk0, accd);
    accd = mfma16(qa1, mk1, accd);
    acck = mfma16(qa0, kt0, acck);
    acck = mfma16(qa1, kt1, acck);

    float vt[4], vd[4];
    #pragma unroll
    for (int ct = 0; ct < 4; ++ct) {
        vt[ct] = VtotF[b * 64 + ct * 16 + ln];
        vd[ct] = VDs[b * 64 + ct * 16 + ln];
    }

    float inv[4];
    #pragma unroll
    for (int r = 0; r < 4; ++r) inv[r] = 1.f / (4096.f + accd[r]);

    #pragma unroll
    for (int ct = 0; ct < 4; ++ct)
        #pragma unroll
        for (int r = 0; r < 4; ++r)
            out[(size_t)(R0 + quad * 4 + r) * HD + ct * 16 + ln] =
                (vt[ct] + acc[ct][r] + acck[r] * vd[ct]) * inv[r];
}

// ---------------------------------------------------------------------------
extern "C" void kernel_launch(void* const* d_in, const int* in_sizes, int n_in,
                              void* d_out, int out_size, void* d_ws, size_t ws_size,
                              hipStream_t stream)
{
    const float* feat = (const float*)d_in[0];
    const float* Wq = (const float*)d_in[1];
    const float* bq = (const float*)d_in[2];
    const float* Wk = (const float*)d_in[3];
    const float* bk = (const float*)d_in[4];
    const float* Wv = (const float*)d_in[5];
    const float* bv = (const float*)d_in[6];
    float* out = (float*)d_out;

    char* ws = (char*)d_ws;
    __hip_bfloat16* qsb    = (__hip_bfloat16*)(ws + 0);                  // 2 MB
    __hip_bfloat16* Mpart  = (__hip_bfloat16*)(ws + (2u << 20));         // 4 MB
    float*          kpart  = (float*)(ws + (6u << 20));                  // 128 KB
    float*          vpart  = (float*)(ws + (6u << 20) + 131072);         // 128 KB
    float*          kedge  = (float*)(ws + (6u << 20) + 262144);         // 8 KB
    __hip_bfloat16* MTm    = (__hip_bfloat16*)(ws + (6u << 20) + 270336);// 32 KB
    float*          mktotF = (float*)(ws + (6u << 20) + 303104);         // 1 KB
    float*          ktotF  = (float*)(ws + (6u << 20) + 304128);         // 1 KB
    float*          VDs    = (float*)(ws + (6u << 20) + 305152);         // 1 KB
    float*          VtotF  = (float*)(ws + (6u << 20) + 306176);         // 1 KB
    __hip_bfloat16* Wb     = (__hip_bfloat16*)(ws + (6u << 20) + 307200);// 24 KB
    int*            Mcount = (int*)(ws + (6u << 20) + 331776);           // 16 B

    wpack_kernel<<<dim3(3), dim3(256), 0, stream>>>(Wq, Wk, Wv, Wb, Mcount);
    projm_kernel<<<dim3(512), dim3(256), 0, stream>>>(
        feat, Wb, bq, bk, bv, qsb, kpart, vpart, Mpart, kedge,
        Mcount, MTm, mktotF, ktotF, VDs, VtotF);
    out_kernel<<<dim3(1024), dim3(64), 0, stream>>>(
        qsb, MTm, mktotF, ktotF, VDs, VtotF, out);
}

// Round 16
// 82.307 us; speedup vs baseline: 1.5440x; 1.5440x over previous
//
#include <hip/hip_runtime.h>
#include <hip/hip_bf16.h>
#include <math.h>

#define SEQ 4096
#define HD  64
#define NBATCH 4

#define EM1   1.71828182845904523536f
#define INVD5 (1.0f/(4096.f + 5.f*EM1))
#define INVD4 (1.0f/(4096.f + 4.f*EM1))
#define INVD3 (1.0f/(4096.f + 3.f*EM1))

typedef __attribute__((ext_vector_type(8))) short short8;
typedef __attribute__((ext_vector_type(4))) float f32x4;

__device__ __forceinline__ f32x4 mfma16(short8 a, short8 b, f32x4 c) {
    return __builtin_amdgcn_mfma_f32_16x16x32_bf16(a, b, c, 0, 0, 0);
}

__device__ __forceinline__ short bfs(float x) {
    __hip_bfloat16 h = __float2bfloat16(x);
    return *(short*)&h;
}

__device__ __forceinline__ short8 pack8(float4 a, float4 b) {
    short8 r;
    r[0] = bfs(a.x); r[1] = bfs(a.y); r[2] = bfs(a.z); r[3] = bfs(a.w);
    r[4] = bfs(b.x); r[5] = bfs(b.y); r[6] = bfs(b.z); r[7] = bfs(b.w);
    return r;
}

__device__ __forceinline__ float b2f(__hip_bfloat16 h) { return __bfloat162float(h); }

// ---------------------------------------------------------------------------
// Kernel 0: prepack W to bf16 (Wq scaled by exact 0.125).  3 blocks.
// ---------------------------------------------------------------------------
__global__ __launch_bounds__(256) void wpack_kernel(
    const float* __restrict__ Wq, const float* __restrict__ Wk,
    const float* __restrict__ Wv, __hip_bfloat16* __restrict__ Wb)
{
    const int blk = blockIdx.x, tid = threadIdx.x;
    const float* W = (blk == 0) ? Wq : (blk == 1) ? Wk : Wv;
    const float s = (blk == 0) ? 0.125f : 1.f;
    const float* src = W + tid * 16;
    float4 a0 = *(const float4*)(src);
    float4 a1 = *(const float4*)(src + 4);
    float4 a2 = *(const float4*)(src + 8);
    float4 a3 = *(const float4*)(src + 12);
    a0.x*=s; a0.y*=s; a0.z*=s; a0.w*=s;
    a1.x*=s; a1.y*=s; a1.z*=s; a1.w*=s;
    a2.x*=s; a2.y*=s; a2.z*=s; a2.w*=s;
    a3.x*=s; a3.y*=s; a3.z*=s; a3.w*=s;
    __hip_bfloat16* dst = Wb + blk * 4096 + tid * 16;
    *(short8*)(dst)     = pack8(a0, a1);
    *(short8*)(dst + 8) = pack8(a2, a3);
}

// ---------------------------------------------------------------------------
// Kernel 1: fused projection + M-chunk GEMM.  512 blocks x 128 thr (2 waves,
// 32 rows = one 32-t chunk of one batch).
//  - q -> qsb (bf16, prescaled)
//  - k,v -> transposed LDS tiles only (no global round trip)
//  - v halo rows (t0-2,t0-1,t0+32,t0+33) recomputed via MFMA (A lanes 0,1)
//  - locv5^T built in LDS, then 8 MFMAs: Mpart[chunk] = k^T · locv5
//  - kpart/vpart column sums; blocks at chunk 0/127 export 8 edge k-rows
// ---------------------------------------------------------------------------
__global__ __launch_bounds__(128) void projm_kernel(
    const float* __restrict__ feat, const __hip_bfloat16* __restrict__ Wb,
    const float* __restrict__ bq, const float* __restrict__ bk,
    const float* __restrict__ bv,
    __hip_bfloat16* __restrict__ qsb, float* __restrict__ kpart,
    float* __restrict__ vpart, __hip_bfloat16* __restrict__ Mpart,
    float* __restrict__ kedge)
{
    __shared__ __hip_bfloat16 kT[64 * 40];    // [h][t-local 0..31]
    __shared__ __hip_bfloat16 vT[64 * 40];    // [h][idx 0..35] = t0-2 .. t0+33
    __shared__ __hip_bfloat16 lvt[64 * 40];   // locv5^T [h][t-local 0..31]
    __shared__ float kred[2][64];
    __shared__ float vred[2][64];

    const int tid  = threadIdx.x;
    const int wave = tid >> 6, lane = tid & 63;
    const int quad = lane >> 4, ln = lane & 15;
    const int R0 = blockIdx.x * 32;            // [0, B*S)
    const int b  = R0 >> 12;
    const int t0 = R0 & (SEQ - 1);
    const int chunk = blockIdx.x & 127;

    // main A-fragments (32 rows)
    short8 af0, af1;
    {
        const float* fp = feat + (size_t)(R0 + wave * 16 + ln) * HD + quad * 8;
        af0 = pack8(*(const float4*)(fp),      *(const float4*)(fp + 4));
        af1 = pack8(*(const float4*)(fp + 32), *(const float4*)(fp + 36));
    }

    // halo A-fragments: wave0 -> rows t0-2,t0-1 (lanes ln=0,1); wave1 -> t0+32,t0+33
    short8 hf0, hf1;
    const bool hflag = (wave == 0) ? (t0 > 0) : (t0 < SEQ - 32);
    {
        const int hrow = (wave == 0) ? (t0 - 2 + ln) : (t0 + 32 + ln);
        if (ln < 2 && hflag) {
            const float* fp = feat + ((size_t)(b << 12) + hrow) * HD + quad * 8;
            hf0 = pack8(*(const float4*)(fp),      *(const float4*)(fp + 4));
            hf1 = pack8(*(const float4*)(fp + 32), *(const float4*)(fp + 36));
        } else {
            #pragma unroll
            for (int j = 0; j < 8; ++j) { hf0[j] = 0; hf1[j] = 0; }
        }
    }

    const float* Bs[3] = {bq, bk, bv};

    #pragma unroll
    for (int m = 0; m < 3; ++m) {
        const __hip_bfloat16* W = Wb + m * 4096;
        const float* bias = Bs[m];
        #pragma unroll
        for (int ct = 0; ct < 4; ++ct) {
            const int col = ct * 16 + ln;
            const __hip_bfloat16* wp = W + col * 64 + quad * 8;
            short8 b0 = *(const short8*)(wp);
            short8 b1 = *(const short8*)(wp + 32);
            f32x4 c = {};
            c = mfma16(af0, b0, c);
            c = mfma16(af1, b1, c);

            if (m == 0) {
                const float bl = bias[col] * 0.125f;
                #pragma unroll
                for (int r = 0; r < 4; ++r)
                    qsb[(size_t)(R0 + wave * 16 + quad * 4 + r) * HD + col] =
                        __float2bfloat16(c[r] + bl);
            } else if (m == 1) {
                const float bl = bias[col];
                float tot = c[0] + c[1] + c[2] + c[3];
                tot += __shfl_xor(tot, 16);
                tot += __shfl_xor(tot, 32);
                if (quad == 0) kred[wave][col] = tot;
                #pragma unroll
                for (int r = 0; r < 4; ++r)
                    kT[col * 40 + wave * 16 + quad * 4 + r] =
                        __float2bfloat16(c[r] + bl);
            } else {
                const float bl = bias[col];
                float tot = c[0] + c[1] + c[2] + c[3];
                tot += __shfl_xor(tot, 16);
                tot += __shfl_xor(tot, 32);
                if (quad == 0) vred[wave][col] = tot;
                #pragma unroll
                for (int r = 0; r < 4; ++r)
                    vT[col * 40 + 2 + wave * 16 + quad * 4 + r] =
                        __float2bfloat16(c[r] + bl);
                // halo rows for this ct (reuse b0/b1): C rows 0,1 = halo
                f32x4 hc = {};
                hc = mfma16(hf0, b0, hc);
                hc = mfma16(hf1, b1, hc);
                if (quad == 0) {
                    const int base = (wave == 0) ? 0 : 34;
                    vT[col * 40 + base]     = __float2bfloat16(hflag ? hc[0] + bl : 0.f);
                    vT[col * 40 + base + 1] = __float2bfloat16(hflag ? hc[1] + bl : 0.f);
                }
            }
        }
    }
    __syncthreads();

    // column-sum partials (128 per batch)
    if (tid < 64) {
        kpart[(size_t)blockIdx.x * 64 + tid] =
            kred[0][tid] + kred[1][tid] + 32.f * bk[tid];
        vpart[(size_t)blockIdx.x * 64 + tid] =
            vred[0][tid] + vred[1][tid] + 32.f * bv[tid];
    }

    // locv5^T: thread (h, wave) -> 16 t's; window idx tl..tl+4 == t-2..t+2
    {
        const int h = tid & 63;
        const int tb = wave * 16;
        float w[21];
        #pragma unroll
        for (int j = 0; j < 21; ++j) w[j] = b2f(vT[h * 40 + tb + j]);
        #pragma unroll
        for (int i = 0; i < 16; ++i)
            lvt[h * 40 + tb + i] =
                __float2bfloat16(w[i] + w[i+1] + w[i+2] + w[i+3] + w[i+4]);
    }

    // export edge k rows for mktot closed form
    if (chunk == 0) {
        #pragma unroll
        for (int i = 0; i < 2; ++i) {
            const int idx = i * 128 + tid;
            const int t = idx >> 6, h = idx & 63;
            kedge[b * 512 + t * 64 + h] = b2f(kT[h * 40 + t]);
        }
    } else if (chunk == 127) {
        #pragma unroll
        for (int i = 0; i < 2; ++i) {
            const int idx = i * 128 + tid;
            const int t = idx >> 6, h = idx & 63;
            kedge[b * 512 + (4 + t) * 64 + h] = b2f(kT[h * 40 + 28 + t]);
        }
    }
    __syncthreads();

    // GEMM: M_chunk[h1][h2] = sum_t k[t][h1]*locv5[t][h2], K=32, 8 MFMAs/wave
    __hip_bfloat16* mp = Mpart + (size_t)(b * 128 + chunk) * 4096;
    #pragma unroll
    for (int p = 0; p < 2; ++p) {
        const int strip = wave * 2 + p;
        short8 a = *(const short8*)&kT[(strip * 16 + ln) * 40 + quad * 8];
        #pragma unroll
        for (int ct = 0; ct < 4; ++ct) {
            short8 bb = *(const short8*)&lvt[(ct * 16 + ln) * 40 + quad * 8];
            f32x4 acc = {};
            acc = mfma16(a, bb, acc);
            #pragma unroll
            for (int r = 0; r < 4; ++r)
                mp[(strip * 16 + quad * 4 + r) * 64 + ct * 16 + ln] =
                    __float2bfloat16(acc[r]);
        }
    }
}

// ---------------------------------------------------------------------------
// Kernel 2: grid (65, B).  x<64: MTm[h2][h1] = bf16(EM1*INVD5 * sum_c Mpart).
// x==64: prep — ktot/Vtot from partials, mktot closed form (kedge), VDs.
// ---------------------------------------------------------------------------
__global__ __launch_bounds__(256) void redprep_kernel(
    const __hip_bfloat16* __restrict__ Mpart, const float* __restrict__ kpart,
    const float* __restrict__ vpart, const float* __restrict__ kedge,
    __hip_bfloat16* __restrict__ MTm, float* __restrict__ mktotF,
    float* __restrict__ ktotF, float* __restrict__ VDs,
    float* __restrict__ VtotF)
{
    __shared__ float red[4][64];
    __shared__ float red2[4][64];
    const int b = blockIdx.y, x = blockIdx.x;
    const int tid = threadIdx.x;
    const int g = tid >> 6, h2 = tid & 63;

    if (x < 64) {
        const int h1 = x;
        float s = 0.f;
        for (int c = g * 32; c < g * 32 + 32; ++c)
            s += b2f(Mpart[(size_t)(b * 128 + c) * 4096 + h1 * 64 + h2]);
        red[g][h2] = s;
        __syncthreads();
        if (tid < 64)
            MTm[(size_t)b * 4096 + tid * 64 + h1] = __float2bfloat16(
                (EM1 * INVD5) * (red[0][tid] + red[1][tid] + red[2][tid] + red[3][tid]));
        return;
    }

    // prep
    {
        float kp = 0.f, vp = 0.f;
        for (int j = 0; j < 32; ++j) {
            kp += kpart[(size_t)(b * 128 + g * 32 + j) * 64 + h2];
            vp += vpart[(size_t)(b * 128 + g * 32 + j) * 64 + h2];
        }
        red[g][h2] = kp;
        red2[g][h2] = vp;
    }
    __syncthreads();
    if (tid < 64) {
        const int hh = tid;
        const float kt = red[0][hh] + red[1][hh] + red[2][hh] + red[3][hh];
        const float vt = red2[0][hh] + red2[1][hh] + red2[2][hh] + red2[3][hh];
        const float e0 = kedge[b * 512 + 0 * 64 + hh];
        const float e1 = kedge[b * 512 + 1 * 64 + hh];
        const float e2 = kedge[b * 512 + 2 * 64 + hh];
        const float e3 = kedge[b * 512 + 3 * 64 + hh];
        const float f0 = kedge[b * 512 + 4 * 64 + hh];
        const float f1 = kedge[b * 512 + 5 * 64 + hh];
        const float f2 = kedge[b * 512 + 6 * 64 + hh];
        const float f3 = kedge[b * 512 + 7 * 64 + hh];
        const float Sint = 5.f*kt - 4.f*e0 - 3.f*e1 - 2.f*e2 - e3
                         - f0 - 2.f*f1 - 3.f*f2 - 4.f*f3;
        const float SlocD = Sint * INVD5
                          + (e0+e1+e2 + f1+f2+f3) * INVD3
                          + (e0+e1+e2+e3 + f0+f1+f2+f3) * INVD4;
        mktotF[b * 64 + hh] = kt * (4092.f*INVD5 + 2.f*INVD4 + 2.f*INVD3) + EM1 * SlocD;
        ktotF[b * 64 + hh]  = kt;
        VDs[b * 64 + hh]    = INVD5 * vt;
        VtotF[b * 64 + hh]  = vt;
    }
}

// ---------------------------------------------------------------------------
// Kernel 3: out = (Vtot + qs·Mmain + (qs·ktot)·VDs) / (4096 + qs·mktot).
// grid 1024 x 64.  12 MFMAs; denominators & ktot-dot via uniform-B trick.
// ---------------------------------------------------------------------------
__global__ __launch_bounds__(64) void out_kernel(
    const __hip_bfloat16* __restrict__ qsb, const __hip_bfloat16* __restrict__ MTm,
    const float* __restrict__ mktotF, const float* __restrict__ ktotF,
    const float* __restrict__ VDs, const float* __restrict__ VtotF,
    float* __restrict__ out)
{
    const int tid = threadIdx.x;
    const int quad = tid >> 4, ln = tid & 15;
    const int R0 = blockIdx.x * 16;
    const int b = R0 >> 12;

    short8 qa0, qa1;
    {
        const __hip_bfloat16* qp = qsb + (size_t)(R0 + ln) * HD + quad * 8;
        qa0 = *(const short8*)qp;
        qa1 = *(const short8*)(qp + 32);
    }

    const __hip_bfloat16* mtb = MTm + (size_t)b * 4096;
    f32x4 acc[4];
    #pragma unroll
    for (int ct = 0; ct < 4; ++ct) {
        short8 b0 = *(const short8*)(mtb + (ct * 16 + ln) * 64 + quad * 8);
        short8 b1 = *(const short8*)(mtb + (ct * 16 + ln) * 64 + 32 + quad * 8);
        f32x4 c = {};
        c = mfma16(qa0, b0, c);
        c = mfma16(qa1, b1, c);
        acc[ct] = c;
    }

    // uniform-B fragments: every lane holds the same vector slice
    short8 mk0, mk1, kt0, kt1;
    #pragma unroll
    for (int j = 0; j < 8; ++j) {
        mk0[j] = bfs(mktotF[b * 64 + quad * 8 + j]);
        mk1[j] = bfs(mktotF[b * 64 + 32 + quad * 8 + j]);
        kt0[j] = bfs(ktotF[b * 64 + quad * 8 + j]);
        kt1[j] = bfs(ktotF[b * 64 + 32 + quad * 8 + j]);
    }
    f32x4 accd = {}, acck = {};
    accd = mfma16(qa0, mk0, accd);
    accd = mfma16(qa1, mk1, accd);     // den per row (lane-uniform)
    acck = mfma16(qa0, kt0, acck);
    acck = mfma16(qa1, kt1, acck);     // qs·ktot per row

    float vt[4], vd[4];
    #pragma unroll
    for (int ct = 0; ct < 4; ++ct) {
        vt[ct] = VtotF[b * 64 + ct * 16 + ln];
        vd[ct] = VDs[b * 64 + ct * 16 + ln];
    }

    float inv[4];
    #pragma unroll
    for (int r = 0; r < 4; ++r) inv[r] = 1.f / (4096.f + accd[r]);

    #pragma unroll
    for (int ct = 0; ct < 4; ++ct)
        #pragma unroll
        for (int r = 0; r < 4; ++r)
            out[(size_t)(R0 + quad * 4 + r) * HD + ct * 16 + ln] =
                (vt[ct] + acc[ct][r] + acck[r] * vd[ct]) * inv[r];
}

// ---------------------------------------------------------------------------
extern "C" void kernel_launch(void* const* d_in, const int* in_sizes, int n_in,
                              void* d_out, int out_size, void* d_ws, size_t ws_size,
                              hipStream_t stream)
{
    const float* feat = (const float*)d_in[0];
    const float* Wq = (const float*)d_in[1];
    const float* bq = (const float*)d_in[2];
    const float* Wk = (const float*)d_in[3];
    const float* bk = (const float*)d_in[4];
    const float* Wv = (const float*)d_in[5];
    const float* bv = (const float*)d_in[6];
    float* out = (float*)d_out;

    char* ws = (char*)d_ws;
    __hip_bfloat16* qsb    = (__hip_bfloat16*)(ws + 0);                  // 2 MB
    __hip_bfloat16* Mpart  = (__hip_bfloat16*)(ws + (2u << 20));         // 4 MB
    float*          kpart  = (float*)(ws + (6u << 20));                  // 128 KB
    float*          vpart  = (float*)(ws + (6u << 20) + 131072);         // 128 KB
    float*          kedge  = (float*)(ws + (6u << 20) + 262144);         // 8 KB
    __hip_bfloat16* MTm    = (__hip_bfloat16*)(ws + (6u << 20) + 270336);// 32 KB
    float*          mktotF = (float*)(ws + (6u << 20) + 303104);         // 1 KB
    float*          ktotF  = (float*)(ws + (6u << 20) + 304128);         // 1 KB
    float*          VDs    = (float*)(ws + (6u << 20) + 305152);         // 1 KB
    float*          VtotF  = (float*)(ws + (6u << 20) + 306176);         // 1 KB
    __hip_bfloat16* Wb     = (__hip_bfloat16*)(ws + (6u << 20) + 307200);// 24 KB

    wpack_kernel<<<dim3(3), dim3(256), 0, stream>>>(Wq, Wk, Wv, Wb);
    projm_kernel<<<dim3(512), dim3(128), 0, stream>>>(
        feat, Wb, bq, bk, bv, qsb, kpart, vpart, Mpart, kedge);
    redprep_kernel<<<dim3(65, NBATCH), dim3(256), 0, stream>>>(
        Mpart, kpart, vpart, kedge, MTm, mktotF, ktotF, VDs, VtotF);
    out_kernel<<<dim3(1024), dim3(64), 0, stream>>>(
        qsb, MTm, mktotF, ktotF, VDs, VtotF, out);
}